// Round 1
// baseline (461.451 us; speedup 1.0000x reference)
//
#include <hip/hip_runtime.h>

#define HD   128          // hidden dim
#define SEQ  15           // enc and dec lengths
#define BN   32           // batch rows per block
#define LDH  168          // hbuf row stride in bf16 elems (336B, 16B-aligned, 2-way-max bank alias)
#define KT   5            // K tiles of 32 (128 h + 4 x + 28 pad)
#define NTHR 512          // 8 waves

typedef __bf16 bf16x8 __attribute__((ext_vector_type(8)));
typedef unsigned short us8 __attribute__((ext_vector_type(8)));
typedef float f32x4 __attribute__((ext_vector_type(4)));

__device__ __forceinline__ unsigned short f2bf(float f) {
  unsigned int u = __builtin_bit_cast(unsigned int, f);
  u += 0x7fffu + ((u >> 16) & 1u);          // RNE; inputs are never NaN here
  return (unsigned short)(u >> 16);
}
__device__ __forceinline__ float bfl(unsigned int u) {   // low bf16 -> f32
  return __builtin_bit_cast(float, u << 16);
}
__device__ __forceinline__ float bfh(unsigned int u) {   // high bf16 -> f32
  return __builtin_bit_cast(float, u & 0xffff0000u);
}
__device__ __forceinline__ float sigm(float v) {
  return __builtin_amdgcn_rcpf(1.0f + __expf(-v));       // inf-safe at both ends
}
__device__ __forceinline__ float tanh_(float v) {
  return 1.0f - 2.0f * __builtin_amdgcn_rcpf(1.0f + __expf(2.0f * v)); // inf-safe
}

__global__ __launch_bounds__(NTHR, 2) void lstm_encdec_kernel(
    const float* __restrict__ x,
    const float* __restrict__ eWih, const float* __restrict__ eWhh,
    const float* __restrict__ ebih, const float* __restrict__ ebhh,
    const float* __restrict__ dWih, const float* __restrict__ dWhh,
    const float* __restrict__ dbih, const float* __restrict__ dbhh,
    const float* __restrict__ oW,  const float* __restrict__ ob,
    float* __restrict__ out)
{
  const int tid  = (int)threadIdx.x;
  const int wv   = tid >> 6;        // wave 0..7: owns h-columns [wv*16, wv*16+16)
  const int lane = tid & 63;
  const int l15  = lane & 15;
  const int lk   = lane >> 4;       // 0..3
  const int b0   = (int)blockIdx.x * BN;

  __shared__ alignas(16) unsigned short hbuf[BN][LDH];  // h (bf16) + x-slot(128..131) + zero pad
  __shared__ float ow_l[4][132];                        // out_W, padded stride
  __shared__ float ob_l[4];

  bf16x8 bw[4][KT];   // B-fragments: 4 gate groups x 5 K-tiles (80 VGPRs)
  float  bias[4];
  f32x4  cst[2], hst[2];

  // ---- zero LDS (covers x-slot + pad cols) ----
  for (int i = tid; i < BN * LDH; i += NTHR) ((unsigned short*)hbuf)[i] = 0;

  #pragma unroll
  for (int m = 0; m < 2; ++m)
    #pragma unroll
    for (int j = 0; j < 4; ++j) { cst[m][j] = 0.0f; hst[m][j] = 0.0f; }

  // ---- weight loader: builds B-frags for B[k][gate] = W[gate][k] (+ decoder fold) ----
  auto load_w = [&](const float* Wih, const float* Whh,
                    const float* bih, const float* bhh, bool fold) {
    #pragma unroll
    for (int g = 0; g < 4; ++g) {
      const int gc = g * HD + wv * 16 + l15;     // gate row this lane serves
      float wi[4];
      #pragma unroll
      for (int d = 0; d < 4; ++d) wi[d] = Wih[gc * 4 + d];
      #pragma unroll
      for (int kt = 0; kt < KT; ++kt) {
        const int k0 = kt * 32 + lk * 8;
        float v[8];
        if (k0 < HD) {
          const float4* p = (const float4*)&Whh[(size_t)gc * HD + k0];
          const float4 u0 = p[0], u1 = p[1];
          v[0]=u0.x; v[1]=u0.y; v[2]=u0.z; v[3]=u0.w;
          v[4]=u1.x; v[5]=u1.y; v[6]=u1.z; v[7]=u1.w;
          if (fold) {       // W' = Whh^T + out_W^T @ Wih^T  (decoder feedback folded in)
            #pragma unroll
            for (int j = 0; j < 8; ++j) {
              float s = v[j];
              #pragma unroll
              for (int d = 0; d < 4; ++d) s += wi[d] * oW[d * HD + k0 + j];
              v[j] = s;
            }
          }
        } else {            // K-tile 4: rows 128..131 = Wih^T, rest zero
          #pragma unroll
          for (int j = 0; j < 8; ++j) {
            v[j] = 0.0f;
            if (j < 4 && lk == 0) v[j] = wi[j];   // j is compile-time: no dyn index
          }
        }
        us8 u;
        #pragma unroll
        for (int j = 0; j < 8; ++j) u[j] = f2bf(v[j]);
        bw[g][kt] = __builtin_bit_cast(bf16x8, u);
      }
      float bb = bih[gc] + bhh[gc];
      if (fold) {
        #pragma unroll
        for (int d = 0; d < 4; ++d) bb += ob[d] * Wih[gc * 4 + d];
      }
      bias[g] = bb;
    }
  };

  auto mfma_step = [&](f32x4 (&acc)[2][4]) {
    #pragma unroll
    for (int m = 0; m < 2; ++m)
      #pragma unroll
      for (int g = 0; g < 4; ++g)
        #pragma unroll
        for (int j = 0; j < 4; ++j) acc[m][g][j] = bias[g];
    #pragma unroll
    for (int kt = 0; kt < KT; ++kt) {
      #pragma unroll
      for (int m = 0; m < 2; ++m) {
        const bf16x8 a = __builtin_bit_cast(bf16x8,
            *(const uint4*)&hbuf[m * 16 + l15][kt * 32 + lk * 8]);
        #pragma unroll
        for (int g = 0; g < 4; ++g)
          acc[m][g] = __builtin_amdgcn_mfma_f32_16x16x32_bf16(a, bw[g][kt], acc[m][g], 0, 0, 0);
      }
    }
  };

  auto act_update = [&](f32x4 (&acc)[2][4]) {
    #pragma unroll
    for (int m = 0; m < 2; ++m) {
      #pragma unroll
      for (int j = 0; j < 4; ++j) {
        const float iv = sigm(acc[m][0][j]);
        const float fv = sigm(acc[m][1][j]);
        const float gv = tanh_(acc[m][2][j]);
        const float ov = sigm(acc[m][3][j]);
        const float cv = fv * cst[m][j] + iv * gv;
        cst[m][j] = cv;
        hst[m][j] = ov * tanh_(cv);
      }
    }
  };

  auto write_h = [&]() {
    #pragma unroll
    for (int m = 0; m < 2; ++m)
      #pragma unroll
      for (int j = 0; j < 4; ++j)
        hbuf[m * 16 + lk * 4 + j][wv * 16 + l15] = f2bf(hst[m][j]);
  };

  auto proj = [&](int b, int d) {   // out_b[d] + sum_k h[b][k] * out_W[d][k]  (h from LDS bf16)
    float s = ob_l[d];
    #pragma unroll
    for (int k = 0; k < HD; k += 8) {
      const uint4 hv = *(const uint4*)&hbuf[b][k];
      const float* wr = &ow_l[d][k];
      s += bfl(hv.x) * wr[0] + bfh(hv.x) * wr[1]
         + bfl(hv.y) * wr[2] + bfh(hv.y) * wr[3]
         + bfl(hv.z) * wr[4] + bfh(hv.z) * wr[5]
         + bfl(hv.w) * wr[6] + bfh(hv.w) * wr[7];
    }
    return s;
  };

  // ---- encoder ----
  load_w(eWih, eWhh, ebih, ebhh, false);
  __syncthreads();
  if (tid < BN) {   // stage x_0 into x-slot
    const float4 xv = *(const float4*)&x[(size_t)(b0 + tid) * 60];
    *(unsigned int*)&hbuf[tid][HD]     = (unsigned)f2bf(xv.x) | ((unsigned)f2bf(xv.y) << 16);
    *(unsigned int*)&hbuf[tid][HD + 2] = (unsigned)f2bf(xv.z) | ((unsigned)f2bf(xv.w) << 16);
  }
  __syncthreads();

  for (int t = 0; t < SEQ; ++t) {
    f32x4 acc[2][4];
    mfma_step(acc);
    __syncthreads();                 // all waves done reading h_t / x_t
    act_update(acc);
    write_h();
    if (t < SEQ - 1 && tid < BN) {   // stage x_{t+1}; at t=14 slot keeps x_14 for decoder
      const float4 xv = *(const float4*)&x[(size_t)(b0 + tid) * 60 + (t + 1) * 4];
      *(unsigned int*)&hbuf[tid][HD]     = (unsigned)f2bf(xv.x) | ((unsigned)f2bf(xv.y) << 16);
      *(unsigned int*)&hbuf[tid][HD + 2] = (unsigned)f2bf(xv.z) | ((unsigned)f2bf(xv.w) << 16);
    }
    __syncthreads();                 // h_{t+1} visible
  }

  // ---- phase switch: decoder with folded feedback ----
  cst[0] = hst[0]; cst[1] = hst[1];  // dec c0 = h_enc (exact f32, D-layout matches)
  load_w(dWih, dWhh, dbih, dbhh, true);
  for (int i = tid; i < 4 * HD; i += NTHR) ow_l[i >> 7][i & 127] = oW[i];
  if (tid < 4) ob_l[tid] = ob[tid];
  __syncthreads();
  if (tid < 128) {                   // x-slot = x14 - proj(h_enc): step-0 correction
    const int b = tid >> 2, d = tid & 3;
    const float x0v = proj(b, d);
    const float x14 = x[(size_t)(b0 + b) * 60 + 56 + d];
    hbuf[b][HD + d] = f2bf(x14 - x0v);
  }
  __syncthreads();

  for (int t = 0; t < SEQ; ++t) {
    f32x4 acc[2][4];
    mfma_step(acc);
    __syncthreads();
    act_update(acc);
    write_h();
    if (t == 0 && tid < BN) {        // steps >=1 use pure folded recurrence: x-slot = 0
      *(unsigned int*)&hbuf[tid][HD]     = 0u;
      *(unsigned int*)&hbuf[tid][HD + 2] = 0u;
    }
    __syncthreads();
    if (tid < 128) {                 // prediction = proj(h_new); output only, no feedback
      const int b = tid >> 2, d = tid & 3;
      out[(size_t)(b0 + b) * 60 + t * 4 + d] = proj(b, d);
    }
  }
}

extern "C" void kernel_launch(void* const* d_in, const int* in_sizes, int n_in,
                              void* d_out, int out_size, void* d_ws, size_t ws_size,
                              hipStream_t stream) {
  const float* x    = (const float*)d_in[0];
  const float* eWih = (const float*)d_in[1];
  const float* eWhh = (const float*)d_in[2];
  const float* ebih = (const float*)d_in[3];
  const float* ebhh = (const float*)d_in[4];
  const float* dWih = (const float*)d_in[5];
  const float* dWhh = (const float*)d_in[6];
  const float* dbih = (const float*)d_in[7];
  const float* dbhh = (const float*)d_in[8];
  const float* oW   = (const float*)d_in[9];
  const float* ob   = (const float*)d_in[10];

  const int batch = in_sizes[0] / (SEQ * 4);   // 32768
  dim3 grid(batch / BN), block(NTHR);
  lstm_encdec_kernel<<<grid, block, 0, stream>>>(
      x, eWih, eWhh, ebih, ebhh, dWih, dWhh, dbih, dbhh, oW, ob, (float*)d_out);
}

// Round 2
// 436.458 us; speedup vs baseline: 1.0573x; 1.0573x over previous
//
#include <hip/hip_runtime.h>

#define HD   128          // hidden dim
#define SEQ  15           // enc and dec lengths
#define BN   32           // batch rows per block
#define LDH  168          // hbuf row stride in bf16 elems (336 B)
#define KT   5            // K tiles of 32 (128 h + 4 x + 2 bias-ones + pad)
#define NTHR 512          // 8 waves

typedef __bf16 bf16x8 __attribute__((ext_vector_type(8)));
typedef unsigned short us8 __attribute__((ext_vector_type(8)));
typedef float f32x4 __attribute__((ext_vector_type(4)));

__device__ __forceinline__ unsigned short f2bf(float f) {
  unsigned int u = __builtin_bit_cast(unsigned int, f);
  u += 0x7fffu + ((u >> 16) & 1u);          // RNE
  return (unsigned short)(u >> 16);
}
__device__ __forceinline__ float bfl(unsigned int u) { return __builtin_bit_cast(float, u << 16); }
__device__ __forceinline__ float bfh(unsigned int u) { return __builtin_bit_cast(float, u & 0xffff0000u); }
__device__ __forceinline__ float sigm(float v) { return __builtin_amdgcn_rcpf(1.0f + __expf(-v)); }
__device__ __forceinline__ float tanh_(float v) { return 1.0f - 2.0f * __builtin_amdgcn_rcpf(1.0f + __expf(2.0f * v)); }

__global__ __launch_bounds__(NTHR, 2) void lstm_encdec_kernel(
    const float* __restrict__ x,
    const float* __restrict__ eWih, const float* __restrict__ eWhh,
    const float* __restrict__ ebih, const float* __restrict__ ebhh,
    const float* __restrict__ dWih, const float* __restrict__ dWhh,
    const float* __restrict__ dbih, const float* __restrict__ dbhh,
    const float* __restrict__ oW,  const float* __restrict__ ob,
    float* __restrict__ out)
{
  const int tid  = (int)threadIdx.x;
  const int wv   = tid >> 6;        // wave 0..7: owns gate-cols [wv*16, wv*16+16) of each gate
  const int lane = tid & 63;
  const int l15  = lane & 15;
  const int lk   = lane >> 4;       // 0..3
  const int b0   = (int)blockIdx.x * BN;

  // proj work split: value v=(pb,pd) computed by 4 threads (pq = K-quarter)
  const int pv = tid >> 2, pb = pv >> 2, pd = pv & 3, pq = tid & 3;

  __shared__ alignas(16) unsigned short hb[2][BN][LDH];  // double-buffered h + x-slot + 1.0-cols
  __shared__ alignas(16) unsigned short xbuf[BN][68];    // all x, bf16 (pad 68 for banks)
  __shared__ alignas(16) float obuf[BN][68];             // staged predictions, f32
  __shared__ float ow_l[4][133];
  __shared__ float ob_l[4];

  bf16x8 bw[4][KT];                 // weights: 4 gates x 5 K-tiles (80 VGPRs)
  f32x4  cst[2], hst[2];

  // ---- init: zero both h buffers (incl x-slots and pads) ----
  for (int i = tid; i < 2 * BN * LDH; i += NTHR) ((unsigned short*)hb)[i] = 0;
  #pragma unroll
  for (int m = 0; m < 2; ++m)
    #pragma unroll
    for (int j = 0; j < 4; ++j) { cst[m][j] = 0.0f; hst[m][j] = 0.0f; }

  // ---- weight loader: B[k][gate-col]; bias rides K-rows 132/133 (double-bf16) ----
  auto load_w = [&](const float* Wih, const float* Whh,
                    const float* bih, const float* bhh, bool fold) {
    #pragma unroll
    for (int g = 0; g < 4; ++g) {
      const int gc = g * HD + wv * 16 + l15;
      float wi[4];
      #pragma unroll
      for (int d = 0; d < 4; ++d) wi[d] = Wih[gc * 4 + d];
      float bb = bih[gc] + bhh[gc];
      if (fold) {
        #pragma unroll
        for (int d = 0; d < 4; ++d) bb += ob[d] * wi[d];
      }
      #pragma unroll
      for (int kt = 0; kt < KT - 1; ++kt) {
        const int k0 = kt * 32 + lk * 8;
        const float4* p = (const float4*)&Whh[(size_t)gc * HD + k0];
        const float4 u0 = p[0], u1 = p[1];
        float v[8] = {u0.x, u0.y, u0.z, u0.w, u1.x, u1.y, u1.z, u1.w};
        if (fold) {       // W' = Whh^T + out_W^T @ Wih^T (decoder feedback folded)
          #pragma unroll
          for (int j = 0; j < 8; ++j) {
            float s = v[j];
            #pragma unroll
            for (int d = 0; d < 4; ++d) s += wi[d] * oW[d * HD + k0 + j];
            v[j] = s;
          }
        }
        us8 u;
        #pragma unroll
        for (int j = 0; j < 8; ++j) u[j] = f2bf(v[j]);
        bw[g][kt] = __builtin_bit_cast(bf16x8, u);
      }
      us8 u4 = {0, 0, 0, 0, 0, 0, 0, 0};   // K-tile 4: rows 128..131 = Wih^T, 132/133 = bias hi/lo
      if (lk == 0) {
        #pragma unroll
        for (int j = 0; j < 4; ++j) u4[j] = f2bf(wi[j]);
        const unsigned short bh = f2bf(bb);
        u4[4] = bh;
        u4[5] = f2bf(bb - bfl((unsigned)bh));
      }
      bw[g][KT - 1] = __builtin_bit_cast(bf16x8, u4);
    }
  };

  auto mfma_step = [&](f32x4 (&acc)[2][4], int p) {
    #pragma unroll
    for (int m = 0; m < 2; ++m)
      #pragma unroll
      for (int g = 0; g < 4; ++g)
        #pragma unroll
        for (int j = 0; j < 4; ++j) acc[m][g][j] = 0.0f;
    #pragma unroll
    for (int kt = 0; kt < KT; ++kt) {
      #pragma unroll
      for (int m = 0; m < 2; ++m) {
        const bf16x8 a = __builtin_bit_cast(bf16x8,
            *(const uint4*)&hb[p][m * 16 + l15][kt * 32 + lk * 8]);
        #pragma unroll
        for (int g = 0; g < 4; ++g)
          acc[m][g] = __builtin_amdgcn_mfma_f32_16x16x32_bf16(a, bw[g][kt], acc[m][g], 0, 0, 0);
      }
    }
  };

  auto act_update = [&](f32x4 (&acc)[2][4]) {
    #pragma unroll
    for (int m = 0; m < 2; ++m)
      #pragma unroll
      for (int j = 0; j < 4; ++j) {
        const float iv = sigm(acc[m][0][j]);
        const float fv = sigm(acc[m][1][j]);
        const float gv = tanh_(acc[m][2][j]);
        const float ov = sigm(acc[m][3][j]);
        const float cv = fv * cst[m][j] + iv * gv;
        cst[m][j] = cv;
        hst[m][j] = ov * tanh_(cv);
      }
  };

  auto write_h = [&](int pw) {
    #pragma unroll
    for (int m = 0; m < 2; ++m)
      #pragma unroll
      for (int j = 0; j < 4; ++j)
        hb[pw][m * 16 + lk * 4 + j][wv * 16 + l15] = f2bf(hst[m][j]);
  };

  // distributed projection: all 512 threads; each value by 4 threads, shfl-reduced.
  auto proj = [&](int p) {
    float s = 0.0f;
    #pragma unroll
    for (int c = 0; c < 4; ++c) {
      const int rc = (c + pq) & 3;            // rotation: breaks q-stride bank conflicts
      const int k  = pq * 32 + rc * 8;
      const uint4 hv = *(const uint4*)&hb[p][pb][k];
      const float* w = &ow_l[pd][k];
      s += bfl(hv.x) * w[0] + bfh(hv.x) * w[1]
         + bfl(hv.y) * w[2] + bfh(hv.y) * w[3]
         + bfl(hv.z) * w[4] + bfh(hv.z) * w[5]
         + bfl(hv.w) * w[6] + bfh(hv.w) * w[7];
    }
    s += __shfl_xor(s, 1);
    s += __shfl_xor(s, 2);
    return s + ob_l[pd];
  };

  // ---- one-time staging ----
  load_w(eWih, eWhh, ebih, ebhh, false);
  if (tid < 480) {                   // preload all x -> bf16 LDS (coalesced float4)
    const int b = tid / 15, c = tid % 15;
    const float4 xv = *(const float4*)&x[(size_t)(b0 + b) * 60 + c * 4];
    *(unsigned int*)&xbuf[b][c * 4]     = (unsigned)f2bf(xv.x) | ((unsigned)f2bf(xv.y) << 16);
    *(unsigned int*)&xbuf[b][c * 4 + 2] = (unsigned)f2bf(xv.z) | ((unsigned)f2bf(xv.w) << 16);
  }
  __syncthreads();
  if (tid < 64) {                    // constant-1.0 bias channels, both buffers
    const int buf = tid >> 5, b = tid & 31;
    *(unsigned int*)&hb[buf][b][132] = 0x3F803F80u;
  }
  if (tid < BN) {                    // stage x_0
    const uint2 xv = *(const uint2*)&xbuf[tid][0];
    *(uint2*)&hb[0][tid][128] = xv;
  }
  __syncthreads();

  // ---- encoder: one barrier per step (double-buffered h) ----
  int p = 0;
  #pragma unroll 2
  for (int t = 0; t < SEQ; ++t) {
    f32x4 acc[2][4];
    mfma_step(acc, p);
    act_update(acc);                 // register-private: before the barrier
    write_h(p ^ 1);
    if (t < SEQ - 1 && tid < BN) {   // stage x_{t+1} into the buffer being written
      const uint2 xv = *(const uint2*)&xbuf[tid][(t + 1) * 4];
      *(uint2*)&hb[p ^ 1][tid][128] = xv;
    }
    __syncthreads();
    p ^= 1;
  }
  // p == 1: hb[1] holds h_enc

  // ---- decoder setup: fold feedback, step-0 correction ----
  cst[0] = hst[0]; cst[1] = hst[1];  // dec c0 = h_enc (exact f32)
  load_w(dWih, dWhh, dbih, dbhh, true);
  for (int i = tid; i < 4 * HD; i += NTHR) ow_l[i >> 7][i & 127] = oW[i];
  if (tid < 4) ob_l[tid] = ob[tid];
  __syncthreads();
  {
    const float s = proj(p);         // proj(h_enc)
    if (pq == 0) {
      const float x14 = bfl((unsigned)xbuf[pb][56 + pd]);
      hb[p][pb][128 + pd] = f2bf(x14 - s);   // x-slot = x14 - proj(h_enc)
    }
  }
  __syncthreads();

  // ---- decoder: proj of previous h overlaps current MFMA phase ----
  #pragma unroll 2
  for (int t = 0; t < SEQ; ++t) {
    f32x4 acc[2][4];
    mfma_step(acc, p);
    if (t > 0) {                     // output t-1 = proj(h_t), reads hb[p] like the MFMAs
      const float pr = proj(p);
      if (pq == 0) obuf[pb][(t - 1) * 4 + pd] = pr;
    }
    act_update(acc);
    write_h(p ^ 1);
    if (tid < BN)                    // steps >=1 use pure folded recurrence: x-slot = 0
      *(uint2*)&hb[p ^ 1][tid][128] = (uint2){0u, 0u};
    __syncthreads();
    p ^= 1;
  }
  {
    const float pr = proj(p);        // final output from h_15
    if (pq == 0) obuf[pb][14 * 4 + pd] = pr;
  }
  __syncthreads();

  // ---- single coalesced dump ----
  if (tid < 480) {
    const int b = tid / 15, c = tid % 15;
    const float4 v = *(const float4*)&obuf[b][c * 4];
    *(float4*)&out[(size_t)(b0 + b) * 60 + c * 4] = v;
  }
}

extern "C" void kernel_launch(void* const* d_in, const int* in_sizes, int n_in,
                              void* d_out, int out_size, void* d_ws, size_t ws_size,
                              hipStream_t stream) {
  const float* x    = (const float*)d_in[0];
  const float* eWih = (const float*)d_in[1];
  const float* eWhh = (const float*)d_in[2];
  const float* ebih = (const float*)d_in[3];
  const float* ebhh = (const float*)d_in[4];
  const float* dWih = (const float*)d_in[5];
  const float* dWhh = (const float*)d_in[6];
  const float* dbih = (const float*)d_in[7];
  const float* dbhh = (const float*)d_in[8];
  const float* oW   = (const float*)d_in[9];
  const float* ob   = (const float*)d_in[10];

  const int batch = in_sizes[0] / (SEQ * 4);   // 32768
  dim3 grid(batch / BN), block(NTHR);
  lstm_encdec_kernel<<<grid, block, 0, stream>>>(
      x, eWih, eWhh, ebih, ebhh, dWih, dWhh, dbih, dbhh, oW, ob, (float*)d_out);
}